// Round 4
// baseline (134.959 us; speedup 1.0000x reference)
//
#include <hip/hip_runtime.h>
#include <math.h>

#define NJ   24
#define TPB  256
#define IPW  64            // items per wave (1 per lane)
#define NW   (TPB / 64)    // 4 waves
#define CJ   4             // joints per chunk
#define NCH  6             // chunks

__global__ __launch_bounds__(TPB, 2) void fk_kernel(
    const float* __restrict__ theta,        // Bn*NJ*3
    const float* __restrict__ rest_pose,    // NJ*3
    const float* __restrict__ bone_factor,  // NJ-1
    float* __restrict__ kp3d,               // Bn*NJ*3
    float* __restrict__ orient,             // Bn*NJ*9
    float* __restrict__ l2ws,               // Bn*NJ*16
    int Bn)
{
    constexpr int par[NJ] = {-1,0,0,0,1,2,3,4,5,6,7,8,9,9,9,12,13,14,16,17,18,19,20,21};

    // Wave-private LDS: [wave][item(64)][16 f4] = 64 KB exactly.
    // Column XOR-swizzle by (item & 15) breaks the 64-float stride bank conflict.
    __shared__ float4 ls[NW * IPW * 16];

    const int tid  = threadIdx.x;
    const int w    = tid >> 6;
    const int lane = tid & 63;
    const int items_base = blockIdx.x * TPB + w * IPW;
    const int b = items_base + lane;

    const int n_i = min(IPW, Bn - items_base);
    if (n_i <= 0) return;                 // whole wave out of range; no barriers exist

    float4* lsw = ls + w * (IPW * 16);
    const float* lsf = reinterpret_cast<const float*>(lsw);

    // ---- prefetch full theta item (288 B) into registers ----
    float t[NJ * 3];
    if (b < Bn) {
        const float4* tb4 = reinterpret_cast<const float4*>(theta + (size_t)b * (NJ * 3));
        #pragma unroll
        for (int i = 0; i < 18; ++i) {
            const float4 v = tb4[i];
            t[i*4+0] = v.x; t[i*4+1] = v.y; t[i*4+2] = v.z; t[i*4+3] = v.w;
        }
    }

    float L[NJ][12];   // constant-indexed (fully unrolled) -> registers

    #pragma unroll
    for (int c = 0; c < NCH; ++c) {
        // ---------- compute + stage: every lane owns one item ----------
        if (b < Bn) {
            const int sw = lane & 15;
            #pragma unroll
            for (int jj = 0; jj < CJ; ++jj) {
                const int j = c * CJ + jj;
                const float x = t[j*3+0], y = t[j*3+1], z = t[j*3+2];
                const float n2  = x*x + y*y + z*z + 1e-12f;
                const float ang = sqrtf(n2);
                const float inv = 1.0f / ang;
                const float ux = x*inv, uy = y*inv, uz = z*inv;
                const float s  = __sinf(ang);
                const float cs = __cosf(ang);
                const float ic = 1.0f - cs;
                const float xx = ic*ux*ux, yy = ic*uy*uy, zz = ic*uz*uz;
                const float xy = ic*ux*uy, xz = ic*ux*uz, yz = ic*uy*uz;
                const float sx = s*ux, sy = s*uy, sz = s*uz;
                const float R00 = cs+xx,  R01 = xy-sz, R02 = xz+sy;
                const float R10 = xy+sz,  R11 = cs+yy, R12 = yz-sx;
                const float R20 = xz-sy,  R21 = yz+sx, R22 = cs+zz;

                if (j == 0) {
                    L[0][0]=R00; L[0][1]=R01; L[0][2] =R02; L[0][3] =rest_pose[0];
                    L[0][4]=R10; L[0][5]=R11; L[0][6] =R12; L[0][7] =rest_pose[1];
                    L[0][8]=R20; L[0][9]=R21; L[0][10]=R22; L[0][11]=rest_pose[2];
                } else {
                    const int p = par[j];
                    float bf = bone_factor[j - 1];
                    bf = sqrtf(bf*bf + 1e-36f);
                    const float bx = (rest_pose[j*3+0] - rest_pose[p*3+0]) * bf;
                    const float by = (rest_pose[j*3+1] - rest_pose[p*3+1]) * bf;
                    const float bz = (rest_pose[j*3+2] - rest_pose[p*3+2]) * bf;

                    const float p0=L[p][0], p1=L[p][1], p2 =L[p][2],  p3 =L[p][3];
                    const float p4=L[p][4], p5=L[p][5], p6 =L[p][6],  p7 =L[p][7];
                    const float p8=L[p][8], p9=L[p][9], p10=L[p][10], p11=L[p][11];

                    L[j][0]  = p0*R00 + p1*R10 + p2*R20;
                    L[j][1]  = p0*R01 + p1*R11 + p2*R21;
                    L[j][2]  = p0*R02 + p1*R12 + p2*R22;
                    L[j][3]  = p0*bx  + p1*by  + p2*bz + p3;
                    L[j][4]  = p4*R00 + p5*R10 + p6*R20;
                    L[j][5]  = p4*R01 + p5*R11 + p6*R21;
                    L[j][6]  = p4*R02 + p5*R12 + p6*R22;
                    L[j][7]  = p4*bx  + p5*by  + p6*bz + p7;
                    L[j][8]  = p8*R00 + p9*R10 + p10*R20;
                    L[j][9]  = p8*R01 + p9*R11 + p10*R21;
                    L[j][10] = p8*R02 + p9*R12 + p10*R22;
                    L[j][11] = p8*bx  + p9*by  + p10*bz + p11;
                }

                lsw[lane*16 + ((jj*4+0) ^ sw)] = make_float4(L[j][0], L[j][1], L[j][2],  L[j][3]);
                lsw[lane*16 + ((jj*4+1) ^ sw)] = make_float4(L[j][4], L[j][5], L[j][6],  L[j][7]);
                lsw[lane*16 + ((jj*4+2) ^ sw)] = make_float4(L[j][8], L[j][9], L[j][10], L[j][11]);
                lsw[lane*16 + ((jj*4+3) ^ sw)] = make_float4(0.0f, 0.0f, 0.0f, 1.0f);
            }
        }
        // No barrier: wave-private LDS region; intra-wave DS ordering is in-order.

        // ---------- flush l2ws: 1024 f4, lane-contiguous full lines ----------
        {
            float4* g4 = reinterpret_cast<float4*>(l2ws);
            #pragma unroll
            for (int k = 0; k < 16; ++k) {
                const int g = k * 64 + lane;
                const int i = g >> 4, off = g & 15;
                if (i < n_i)
                    g4[(size_t)(items_base + i) * 96 + c * 16 + off] =
                        lsw[i * 16 + (off ^ (i & 15))];
            }
        }

        // ---------- flush orient: 576 f4 (36 floats/item-chunk) ----------
        {
            float4* g4 = reinterpret_cast<float4*>(orient);
            #pragma unroll
            for (int k = 0; k < 9; ++k) {
                const int g = k * 64 + lane;
                const int i = g / 9, off = g % 9;
                if (i < n_i) {
                    float v[4];
                    #pragma unroll
                    for (int m = 0; m < 4; ++m) {
                        const int f  = off * 4 + m;     // [0,36)
                        const int jj = f / 9, mm = f % 9;
                        const int r  = mm / 3, cc = mm % 3;
                        v[m] = lsf[(i * 16 + ((jj * 4 + r) ^ (i & 15))) * 4 + cc];
                    }
                    g4[(size_t)(items_base + i) * 54 + c * 9 + off] =
                        make_float4(v[0], v[1], v[2], v[3]);
                }
            }
        }

        // ---------- flush kp3d: 192 f4 (12 floats/item-chunk) ----------
        {
            float4* g4 = reinterpret_cast<float4*>(kp3d);
            #pragma unroll
            for (int k = 0; k < 3; ++k) {
                const int g = k * 64 + lane;
                const int i = g / 3, off = g % 3;
                if (i < n_i) {
                    float v[4];
                    #pragma unroll
                    for (int m = 0; m < 4; ++m) {
                        const int f  = off * 4 + m;     // [0,12)
                        const int jj = f / 3, r = f % 3;
                        v[m] = lsf[(i * 16 + ((jj * 4 + r) ^ (i & 15))) * 4 + 3];
                    }
                    g4[(size_t)(items_base + i) * 18 + c * 3 + off] =
                        make_float4(v[0], v[1], v[2], v[3]);
                }
            }
        }
    }
}

extern "C" void kernel_launch(void* const* d_in, const int* in_sizes, int n_in,
                              void* d_out, int out_size, void* d_ws, size_t ws_size,
                              hipStream_t stream) {
    const float* theta       = (const float*)d_in[0];
    const float* rest_pose   = (const float*)d_in[1];
    const float* bone_factor = (const float*)d_in[2];

    const int Bn = in_sizes[0] / (NJ * 3);
    const size_t BNJ = (size_t)Bn * NJ;

    float* out    = (float*)d_out;
    float* kp3d   = out;                // BNJ*3
    float* orient = out + BNJ * 3;      // BNJ*9
    float* l2ws   = out + BNJ * 12;     // BNJ*16

    const int grid = (Bn + TPB - 1) / TPB;
    fk_kernel<<<grid, TPB, 0, stream>>>(theta, rest_pose, bone_factor,
                                        kp3d, orient, l2ws, Bn);
}

// Round 5
// 122.740 us; speedup vs baseline: 1.0996x; 1.0996x over previous
//
#include <hip/hip_runtime.h>
#include <math.h>

#define NJ   24
#define TPB  256
#define IPB  64     // items per block
#define CJ   4      // joints per chunk
#define NCH  6      // chunks
#define ROW  17     // float4 per item per chunk in LDS (16 + 1 pad)

static constexpr int PAR[NJ] = {-1,0,0,0,1,2,3,4,5,6,7,8,9,9,9,12,13,14,16,17,18,19,20,21};

// ---- producer: compute CJ joints of the chain, stage into LDS ----
template<int CC>
__device__ __forceinline__ void compute_chunk(
    bool act, const float* __restrict__ t, float (&L)[NJ][12],
    float4* __restrict__ bc, int lane,
    const float* __restrict__ rest_pose, const float* __restrict__ bone_factor)
{
    if (!act) return;
    #pragma unroll
    for (int jj = 0; jj < CJ; ++jj) {
        const int j = CC * CJ + jj;              // compile-time constant
        const float x = t[jj*3+0], y = t[jj*3+1], z = t[jj*3+2];
        const float ang = sqrtf(x*x + y*y + z*z + 1e-12f);
        const float inv = 1.0f / ang;
        const float ux = x*inv, uy = y*inv, uz = z*inv;
        const float s  = __sinf(ang);
        const float cs = __cosf(ang);
        const float ic = 1.0f - cs;
        const float xx = ic*ux*ux, yy = ic*uy*uy, zz = ic*uz*uz;
        const float xy = ic*ux*uy, xz = ic*ux*uz, yz = ic*uy*uz;
        const float sx = s*ux, sy = s*uy, sz = s*uz;
        const float R00 = cs+xx,  R01 = xy-sz, R02 = xz+sy;
        const float R10 = xy+sz,  R11 = cs+yy, R12 = yz-sx;
        const float R20 = xz-sy,  R21 = yz+sx, R22 = cs+zz;

        if (j == 0) {
            L[0][0]=R00; L[0][1]=R01; L[0][2] =R02; L[0][3] =rest_pose[0];
            L[0][4]=R10; L[0][5]=R11; L[0][6] =R12; L[0][7] =rest_pose[1];
            L[0][8]=R20; L[0][9]=R21; L[0][10]=R22; L[0][11]=rest_pose[2];
        } else {
            const int p = PAR[j];
            float bfv = bone_factor[j - 1];
            bfv = sqrtf(bfv*bfv + 1e-36f);
            const float bx = (rest_pose[j*3+0] - rest_pose[p*3+0]) * bfv;
            const float by = (rest_pose[j*3+1] - rest_pose[p*3+1]) * bfv;
            const float bz = (rest_pose[j*3+2] - rest_pose[p*3+2]) * bfv;

            const float p0=L[p][0], p1=L[p][1], p2 =L[p][2],  p3 =L[p][3];
            const float p4=L[p][4], p5=L[p][5], p6 =L[p][6],  p7 =L[p][7];
            const float p8=L[p][8], p9=L[p][9], p10=L[p][10], p11=L[p][11];

            L[j][0]  = p0*R00 + p1*R10 + p2*R20;
            L[j][1]  = p0*R01 + p1*R11 + p2*R21;
            L[j][2]  = p0*R02 + p1*R12 + p2*R22;
            L[j][3]  = p0*bx  + p1*by  + p2*bz + p3;
            L[j][4]  = p4*R00 + p5*R10 + p6*R20;
            L[j][5]  = p4*R01 + p5*R11 + p6*R21;
            L[j][6]  = p4*R02 + p5*R12 + p6*R22;
            L[j][7]  = p4*bx  + p5*by  + p6*bz + p7;
            L[j][8]  = p8*R00 + p9*R10 + p10*R20;
            L[j][9]  = p8*R01 + p9*R11 + p10*R21;
            L[j][10] = p8*R02 + p9*R12 + p10*R22;
            L[j][11] = p8*bx  + p9*by  + p10*bz + p11;
        }

        bc[lane*ROW + jj*4 + 0] = make_float4(L[j][0], L[j][1], L[j][2],  L[j][3]);
        bc[lane*ROW + jj*4 + 1] = make_float4(L[j][4], L[j][5], L[j][6],  L[j][7]);
        bc[lane*ROW + jj*4 + 2] = make_float4(L[j][8], L[j][9], L[j][10], L[j][11]);
        bc[lane*ROW + jj*4 + 3] = make_float4(0.0f, 0.0f, 0.0f, 1.0f);
    }
}

// ---- consumers: waves 1-3 (192 lanes) flush one chunk from LDS ----
__device__ __forceinline__ void flush_chunk(
    const float4* __restrict__ bc, int c, int ft, int item0, int n_i,
    float4* __restrict__ l2g, float4* __restrict__ org, float4* __restrict__ kpg)
{
    const float* bff = reinterpret_cast<const float*>(bc);

    // l2ws: 1024 f4, contiguous per item-chunk
    #pragma unroll
    for (int k = 0; k < 6; ++k) {
        const int g = k * 192 + ft;
        if (k < 5 || g < 1024) {
            const int i = g >> 4, off = g & 15;
            if (i < n_i)
                l2g[(size_t)(item0 + i) * 96 + c * 16 + off] = bc[i * ROW + off];
        }
    }
    // orient: 576 f4 (36 floats / item-chunk), exact 3 per lane
    #pragma unroll
    for (int k = 0; k < 3; ++k) {
        const int g = k * 192 + ft;
        const int i = g / 9, off = g % 9;
        if (i < n_i) {
            float v[4];
            #pragma unroll
            for (int m = 0; m < 4; ++m) {
                const int f = off * 4 + m;          // [0,36)
                const int jj = f / 9, mm = f % 9;
                const int r = mm / 3, c3 = mm % 3;
                v[m] = bff[(i * ROW + jj * 4 + r) * 4 + c3];
            }
            org[(size_t)(item0 + i) * 54 + c * 9 + off] =
                make_float4(v[0], v[1], v[2], v[3]);
        }
    }
    // kp3d: 192 f4 (12 floats / item-chunk), exact 1 per lane
    {
        const int i = ft / 3, off = ft % 3;
        if (i < n_i) {
            float v[4];
            #pragma unroll
            for (int m = 0; m < 4; ++m) {
                const int f = off * 4 + m;          // [0,12)
                const int jj = f / 3, r = f % 3;
                v[m] = bff[(i * ROW + jj * 4 + r) * 4 + 3];
            }
            kpg[(size_t)(item0 + i) * 18 + c * 3 + off] =
                make_float4(v[0], v[1], v[2], v[3]);
        }
    }
}

#define LOADT(cc, T) do { if (act) { \
    const float4 v0 = tb4[(cc)*3+0], v1 = tb4[(cc)*3+1], v2 = tb4[(cc)*3+2]; \
    T[0]=v0.x; T[1]=v0.y; T[2]=v0.z;  T[3]=v0.w; \
    T[4]=v1.x; T[5]=v1.y; T[6]=v1.z;  T[7]=v1.w; \
    T[8]=v2.x; T[9]=v2.y; T[10]=v2.z; T[11]=v2.w; } } while (0)

__global__ __launch_bounds__(TPB) void fk_kernel(
    const float* __restrict__ theta,
    const float* __restrict__ rest_pose,
    const float* __restrict__ bone_factor,
    float* __restrict__ kp3d,
    float* __restrict__ orient,
    float* __restrict__ l2ws,
    int Bn)
{
    __shared__ float4 buf[2][IPB * ROW];   // 2 x 17,408 B = 34,816 B

    const int tid  = threadIdx.x;
    const int w    = tid >> 6;
    const int lane = tid & 63;
    const int ft   = tid - 64;             // flusher index, valid for w>=1
    const int item0 = blockIdx.x * IPB;
    if (item0 >= Bn) return;
    const int n_i = min(IPB, Bn - item0);

    float L[NJ][12];
    float ta[12], tb_[12];
    const int b = item0 + lane;
    const bool act = (w == 0) && (b < Bn);
    const float4* tb4 = reinterpret_cast<const float4*>(theta + (size_t)b * (NJ * 3));

    float4* l2g = reinterpret_cast<float4*>(l2ws);
    float4* org = reinterpret_cast<float4*>(orient);
    float4* kpg = reinterpret_cast<float4*>(kp3d);

    // prologue: chunk 0 into buf0; prefetch chunk1 theta
    if (w == 0) {
        LOADT(0, ta);
        LOADT(1, tb_);
        compute_chunk<0>(act, ta, L, buf[0], lane, rest_pose, bone_factor);
    }
    __syncthreads();

    // pipeline: producer computes chunk c+1, flushers drain chunk c
    if (w == 0) { LOADT(2, ta);  compute_chunk<1>(act, tb_, L, buf[1], lane, rest_pose, bone_factor); }
    else         flush_chunk(buf[0], 0, ft, item0, n_i, l2g, org, kpg);
    __syncthreads();

    if (w == 0) { LOADT(3, tb_); compute_chunk<2>(act, ta, L, buf[0], lane, rest_pose, bone_factor); }
    else         flush_chunk(buf[1], 1, ft, item0, n_i, l2g, org, kpg);
    __syncthreads();

    if (w == 0) { LOADT(4, ta);  compute_chunk<3>(act, tb_, L, buf[1], lane, rest_pose, bone_factor); }
    else         flush_chunk(buf[0], 2, ft, item0, n_i, l2g, org, kpg);
    __syncthreads();

    if (w == 0) { LOADT(5, tb_); compute_chunk<4>(act, ta, L, buf[0], lane, rest_pose, bone_factor); }
    else         flush_chunk(buf[1], 3, ft, item0, n_i, l2g, org, kpg);
    __syncthreads();

    if (w == 0) {                compute_chunk<5>(act, tb_, L, buf[1], lane, rest_pose, bone_factor); }
    else         flush_chunk(buf[0], 4, ft, item0, n_i, l2g, org, kpg);
    __syncthreads();

    if (w != 0)  flush_chunk(buf[1], 5, ft, item0, n_i, l2g, org, kpg);
}

extern "C" void kernel_launch(void* const* d_in, const int* in_sizes, int n_in,
                              void* d_out, int out_size, void* d_ws, size_t ws_size,
                              hipStream_t stream) {
    const float* theta       = (const float*)d_in[0];
    const float* rest_pose   = (const float*)d_in[1];
    const float* bone_factor = (const float*)d_in[2];

    const int Bn = in_sizes[0] / (NJ * 3);
    const size_t BNJ = (size_t)Bn * NJ;

    float* out    = (float*)d_out;
    float* kp3d   = out;                // BNJ*3
    float* orient = out + BNJ * 3;      // BNJ*9
    float* l2ws   = out + BNJ * 12;     // BNJ*16

    const int grid = (Bn + IPB - 1) / IPB;
    fk_kernel<<<grid, TPB, 0, stream>>>(theta, rest_pose, bone_factor,
                                        kp3d, orient, l2ws, Bn);
}